// Round 2
// baseline (159.787 us; speedup 1.0000x reference)
//
#include <hip/hip_runtime.h>

#define SS 2
#define BB 16
#define KK 128
#define HH 128
#define WW 128
#define HWSZ (HH*WW)
#define EPSF 1e-6f
#define MAXD 181.01933598375618f
#define MAXD2 32768.0f

// ws layout (floats): [0,4096) sumpow[(s*B+b)*K+k], [4096,4128) t1num[s*B+b], [4128,4160) nest[s*B+b]

__device__ __forceinline__ float sigclip(float x) {
    float e = __expf(-x);
    float p = __builtin_amdgcn_rcpf(1.0f + e);
    return fminf(fmaxf(p, 1e-4f), 0.9999f);
}

__global__ void kzero(float* ws, float* out) {
    int i = blockIdx.x * 256 + threadIdx.x;
    if (i < 4160) ws[i] = 0.0f;
    if (i < 3) out[i] = 0.0f;
}

// term1 + n_est: one pass per b (dmin is s-independent), min over d^2, sqrt once.
__global__ void __launch_bounds__(256) kA(const float* __restrict__ hm,
                                          const int* __restrict__ ctr,
                                          const int* __restrict__ reg_mask,
                                          float* __restrict__ ws) {
    const int b = blockIdx.y;
    const int base = blockIdx.x * 1024;
    const int tid = threadIdx.x;
    __shared__ float2 spts[KK];
    if (tid < KK) {
        int mk = reg_mask[b * KK + tid];
        float py = (float)ctr[(b * KK + tid) * 2 + 1];  // pts = ctr[...,::-1] -> y = ctr[...,1]
        float px = (float)ctr[(b * KK + tid) * 2 + 0];
        spts[tid] = mk ? make_float2(py, px) : make_float2(1e9f, 1e9f);  // masked-out: far away
    }
    __syncthreads();
    float t1a = 0.f, t1b = 0.f, nea = 0.f, neb = 0.f;
    for (int r = 0; r < 4; ++r) {
        int i = base + r * 256 + tid;
        float fy = (float)(i >> 7);
        float fx = (float)(i & 127);
        float dmin2 = MAXD2;
        #pragma unroll 8
        for (int k = 0; k < KK; ++k) {
            float2 pt = spts[k];
            float dy = fy - pt.x;
            float dx = fx - pt.y;
            float d2 = fmaf(dx, dx, dy * dy);
            dmin2 = fminf(dmin2, d2);
        }
        float dmin = sqrtf(dmin2);
        float p0 = sigclip(hm[(size_t)(0 * BB + b) * HWSZ + i]);
        float p1 = sigclip(hm[(size_t)(1 * BB + b) * HWSZ + i]);
        t1a = fmaf(p0, dmin, t1a); nea += p0;
        t1b = fmaf(p1, dmin, t1b); neb += p1;
    }
    #pragma unroll
    for (int off = 32; off > 0; off >>= 1) {
        t1a += __shfl_down(t1a, off, 64);
        t1b += __shfl_down(t1b, off, 64);
        nea += __shfl_down(nea, off, 64);
        neb += __shfl_down(neb, off, 64);
    }
    if ((tid & 63) == 0) {
        atomicAdd(&ws[4096 + 0 * BB + b], t1a);
        atomicAdd(&ws[4096 + 1 * BB + b], t1b);
        atomicAdd(&ws[4128 + 0 * BB + b], nea);
        atomicAdd(&ws[4128 + 1 * BB + b], neb);
    }
}

// term2 partial: sum_i (weighted+EPS)^-9 per (s,b,k). Thread = (k, chunk-half);
// d shared across both s; y loop-invariant per thread.
__global__ void __launch_bounds__(256) kB(const float* __restrict__ hm,
                                          const int* __restrict__ ctr,
                                          float* __restrict__ ws) {
    const int b = blockIdx.y;
    const int base = blockIdx.x * 256;
    const int tid = threadIdx.x;
    __shared__ float2 spp[256];
    {
        float p0 = sigclip(hm[(size_t)(0 * BB + b) * HWSZ + base + tid]);
        float p1 = sigclip(hm[(size_t)(1 * BB + b) * HWSZ + base + tid]);
        spp[tid] = make_float2(p0, p1);
    }
    __syncthreads();
    const int k = tid & 127;
    const int half = tid >> 7;
    float py = (float)ctr[(b * KK + k) * 2 + 1];
    float px = (float)ctr[(b * KK + k) * 2 + 0];
    float fy = (float)(blockIdx.x * 2 + half);   // row index is constant per thread
    float dy2 = (fy - py) * (fy - py);
    float acc0 = 0.f, acc1 = 0.f;
    float dx = -px;
    const float2* sp = &spp[half * 128];
    #pragma unroll 4
    for (int j = 0; j < 128; ++j) {
        float d2 = fmaf(dx, dx, dy2);
        float d = sqrtf(d2);
        float t = d - MAXD;                      // weighted = maxd + p*(d-maxd)
        float2 p = sp[j];                        // LDS broadcast (all lanes same addr)
        float w0 = fmaf(p.x, t, MAXD) + EPSF;
        float w1 = fmaf(p.y, t, MAXD) + EPSF;
        float a2 = w0 * w0, a4 = a2 * a2, a8 = a4 * a4;
        float b2 = w1 * w1, b4 = b2 * b2, b8 = b4 * b4;
        acc0 += __builtin_amdgcn_rcpf(a8 * w0);  // x^-9
        acc1 += __builtin_amdgcn_rcpf(b8 * w1);
        dx += 1.0f;
    }
    __shared__ float red0[128], red1[128];
    if (half) { red0[k] = acc0; red1[k] = acc1; }
    __syncthreads();
    if (!half) {
        acc0 += red0[k];
        acc1 += red1[k];
        atomicAdd(&ws[(0 * BB + b) * KK + k], acc0);
        atomicAdd(&ws[(1 * BB + b) * KK + k], acc1);
    }
}

__device__ __forceinline__ float smoothl1(float l) {
    return (l < 0.2f) ? (2.5f * l * l) : (l - 0.1f);
}

// finalize: minn, term2, term1, bounded-IoU, compose outputs. One block per (s,b).
__global__ void __launch_bounds__(128) kC(const float* __restrict__ ws,
                                          const float* __restrict__ wh_map,
                                          const float* __restrict__ reg_map,
                                          const float* __restrict__ reg_gt,
                                          const float* __restrict__ wh_gt,
                                          const int* __restrict__ ind,
                                          const int* __restrict__ reg_mask,
                                          float* __restrict__ out) {
    const int b = blockIdx.x, s = blockIdx.y, k = threadIdx.x;
    float mk = (float)reg_mask[b * KK + k];
    float sp = ws[(s * BB + b) * KK + k];
    float mean = sp * (1.0f / 16384.0f);
    float minn = exp2f(log2f(mean) * (-1.0f / 9.0f));
    float c2 = minn * mk;

    int idx = ind[b * KK + k];
    size_t sb = (size_t)(s * BB + b);
    float rp0 = reg_map[(sb * 2 + 0) * HWSZ + idx];
    float rp1 = reg_map[(sb * 2 + 1) * HWSZ + idx];
    float wp0 = wh_map[(sb * 2 + 0) * HWSZ + idx];
    float wp1 = wh_map[(sb * 2 + 1) * HWSZ + idx];
    float rg0 = reg_gt[(b * KK + k) * 2 + 0];
    float rg1 = reg_gt[(b * KK + k) * 2 + 1];
    float wg0 = wh_gt[(b * KK + k) * 2 + 0];
    float wg1 = wh_gt[(b * KK + k) * 2 + 1];
    float adx = fabsf(rg0 - rp0), ady = fabsf(rg1 - rp1);
    float ldx = 1.0f - fmaxf((wg0 - 2.0f * adx) / (wg0 + 2.0f * adx + EPSF), 0.0f);
    float ldy = 1.0f - fmaxf((wg1 - 2.0f * ady) / (wg1 + 2.0f * ady + EPSF), 0.0f);
    float ldw = 1.0f - fminf(wg0 / (wp0 + EPSF), wp0 / (wg0 + EPSF));
    float ldh = 1.0f - fminf(wg1 / (wp1 + EPSF), wp1 / (wg1 + EPSF));
    float lsum = (smoothl1(ldx) + smoothl1(ldy) + smoothl1(ldw) + smoothl1(ldh)) * mk;

    #pragma unroll
    for (int off = 32; off > 0; off >>= 1) {
        c2   += __shfl_down(c2, off, 64);
        lsum += __shfl_down(lsum, off, 64);
        mk   += __shfl_down(mk, off, 64);
    }
    __shared__ float sred[6];
    int lane = k & 63, wv = k >> 6;
    if (lane == 0) { sred[wv * 3 + 0] = c2; sred[wv * 3 + 1] = lsum; sred[wv * 3 + 2] = mk; }
    __syncthreads();
    if (k == 0) {
        float C2 = sred[0] + sred[3];
        float LS = sred[1] + sred[4];
        float MS = sred[2] + sred[5];
        float valid = (MS > 0.f) ? 1.f : 0.f;
        float den = fmaxf(MS, 1.f);
        float t1 = ws[4096 + s * BB + b] / (ws[4128 + s * BB + b] + EPSF);
        float t2 = C2 / den;
        float hmterm  = (t1 + t2) * valid * (1.0f / 32.0f);
        float iouterm = (LS / (den * 4.0f)) * valid * (1.0f / 32.0f);
        atomicAdd(&out[1], hmterm);
        atomicAdd(&out[2], iouterm);
        atomicAdd(&out[0], hmterm + 0.1f * iouterm);   // HM_WEIGHT=1, WH_WEIGHT=0.1
    }
}

extern "C" void kernel_launch(void* const* d_in, const int* in_sizes, int n_in,
                              void* d_out, int out_size, void* d_ws, size_t ws_size,
                              hipStream_t stream) {
    const float* hm       = (const float*)d_in[0];
    const float* wh_map   = (const float*)d_in[1];
    const float* reg_map  = (const float*)d_in[2];
    const float* reg_gt   = (const float*)d_in[3];
    const float* wh_gt    = (const float*)d_in[4];
    const int*   ind      = (const int*)d_in[5];
    const int*   ctr      = (const int*)d_in[6];
    const int*   reg_mask = (const int*)d_in[7];
    float* out = (float*)d_out;
    float* ws  = (float*)d_ws;

    hipLaunchKernelGGL(kzero, dim3(17), dim3(256), 0, stream, ws, out);
    hipLaunchKernelGGL(kA, dim3(16, BB), dim3(256), 0, stream, hm, ctr, reg_mask, ws);
    hipLaunchKernelGGL(kB, dim3(64, BB), dim3(256), 0, stream, hm, ctr, ws);
    hipLaunchKernelGGL(kC, dim3(BB, SS), dim3(128), 0, stream,
                       ws, wh_map, reg_map, reg_gt, wh_gt, ind, reg_mask, out);
}